// Round 1
// baseline (582.751 us; speedup 1.0000x reference)
//
#include <hip/hip_runtime.h>
#include <stdint.h>

typedef unsigned short u16;
typedef __attribute__((ext_vector_type(8))) short    bf16x8;   // 8 bf16 in 4 VGPRs
typedef __attribute__((ext_vector_type(4))) float    f32x4;
typedef __attribute__((ext_vector_type(8))) unsigned short u16x8;

// ---------- helpers ----------
__device__ __forceinline__ u16 f2bf(float f) {           // fp32 -> bf16, round-nearest-even
    unsigned u = __float_as_uint(f);
    u = (u + 0x7fffu + ((u >> 16) & 1u)) >> 16;
    return (u16)u;
}
__device__ __forceinline__ float bf2f(u16 b) {
    return __uint_as_float(((unsigned)b) << 16);
}
// async global->LDS, 16 bytes per lane (global_load_lds_dwordx4)
__device__ __forceinline__ void gload16(const u16* g, u16* l) {
    __builtin_amdgcn_global_load_lds((const __attribute__((address_space(1))) void*)g,
                                     (__attribute__((address_space(3))) void*)l,
                                     16, 0, 0);
}

// ---------- fp32 -> bf16 cast (vectorized) ----------
__global__ __launch_bounds__(256) void cast_bf16_kernel(const float* __restrict__ in,
                                                        u16* __restrict__ out, int n4) {
    int i = blockIdx.x * 256 + threadIdx.x;
    if (i < n4) {
        float4 f = ((const float4*)in)[i];
        ushort4 o;
        o.x = f2bf(f.x); o.y = f2bf(f.y); o.z = f2bf(f.z); o.w = f2bf(f.w);
        ((ushort4*)out)[i] = o;
    }
}

// ---------- bf16 32x32-tiled transpose: Vt[b][e][s] = V[b][s][e] ----------
__global__ __launch_bounds__(256) void transpose_bf16_kernel(const u16* __restrict__ V,
                                                             u16* __restrict__ Vt) {
    __shared__ u16 tile[32][33];
    const size_t z = blockIdx.z;
    const u16* Vb  = V  + z * (size_t)4096 * 768;
    u16*       Vtb = Vt + z * (size_t)768 * 4096;
    const int c0 = blockIdx.x * 32;           // D (col) tile
    const int r0 = blockIdx.y * 32;           // S (row) tile
    const int t  = threadIdx.x;
    const int lr = t >> 3;                    // 0..31
    const int lc = (t & 7) * 4;               // 0..28
    ushort4 in = *(const ushort4*)&Vb[(size_t)(r0 + lr) * 768 + c0 + lc];
    tile[lr][lc + 0] = in.x; tile[lr][lc + 1] = in.y;
    tile[lr][lc + 2] = in.z; tile[lr][lc + 3] = in.w;
    __syncthreads();
    ushort4 o;
    o.x = tile[lc + 0][lr]; o.y = tile[lc + 1][lr];
    o.z = tile[lc + 2][lr]; o.w = tile[lc + 3][lr];
    *(ushort4*)&Vtb[(size_t)(c0 + lr) * 4096 + r0 + lc] = o;
}

// ---------- m97-style GEMM: C[m][n] = sum_k A[m][k]*B[n][k]  (both row-major bf16) ----------
// 128x128 block tile, BK=32, 4 waves in 2x2, each wave 64x64 via 4x4 MFMA 16x16x32.
// EPI: 0 = +bias[col], bf16 out; 1 = *scale, bf16 out; 2 = fp32 out.
template <int EPI>
__global__ __launch_bounds__(256) void gemm_bt_kernel(
        const u16* __restrict__ A, const u16* __restrict__ B, void* __restrict__ Cv,
        const float* __restrict__ bias, float scale, int K,
        int lda, int ldb, int ldc, long batchA, long batchB, long batchC) {
    __shared__ __align__(16) u16 As[128 * 32];
    __shared__ __align__(16) u16 Bs[128 * 32];

    const int t = threadIdx.x;
    const long z = blockIdx.z;
    const u16* Ab = A + z * batchA + (long)blockIdx.y * 128 * lda;
    const u16* Bb = B + z * batchB + (long)blockIdx.x * 128 * ldb;

    const int lane = t & 63;
    const int wave = t >> 6;
    const int wm = wave >> 1, wn = wave & 1;      // 2x2 wave grid (64x64 each)
    const int quad = lane >> 4;
    const int frow = lane & 15;

    f32x4 acc[4][4];
#pragma unroll
    for (int i = 0; i < 4; i++)
#pragma unroll
        for (int j = 0; j < 4; j++)
#pragma unroll
            for (int e = 0; e < 4; e++) acc[i][j][e] = 0.f;

    // staging: 512 chunks of 16B per 8KB tile; thread t does chunks t and t+256
    const int c0 = t, c1 = t + 256;
    const int ar0 = c0 >> 2, as0 = (c0 & 3) * 8;
    const int ar1 = c1 >> 2, as1 = (c1 & 3) * 8;

    for (int kt = 0; kt < K; kt += 32) {
        gload16(Ab + (long)ar0 * lda + kt + as0, &As[c0 * 8]);
        gload16(Ab + (long)ar1 * lda + kt + as1, &As[c1 * 8]);
        gload16(Bb + (long)ar0 * ldb + kt + as0, &Bs[c0 * 8]);
        gload16(Bb + (long)ar1 * ldb + kt + as1, &Bs[c1 * 8]);
        __syncthreads();

        bf16x8 af[4], bfr[4];
#pragma unroll
        for (int i = 0; i < 4; i++) {
            af[i]  = *(const bf16x8*)&As[(wm * 64 + i * 16 + frow) * 32 + quad * 8];
            bfr[i] = *(const bf16x8*)&Bs[(wn * 64 + i * 16 + frow) * 32 + quad * 8];
        }
#pragma unroll
        for (int i = 0; i < 4; i++)
#pragma unroll
            for (int j = 0; j < 4; j++)
                acc[i][j] = __builtin_amdgcn_mfma_f32_16x16x32_bf16(af[i], bfr[j], acc[i][j], 0, 0, 0);
        __syncthreads();
    }

    // epilogue: C/D layout col = lane&15 (n), row = quad*4 + reg (m)  [m89-verified]
    const int m_base = blockIdx.y * 128 + wm * 64;
    const int n_base = blockIdx.x * 128 + wn * 64;
#pragma unroll
    for (int i = 0; i < 4; i++) {
#pragma unroll
        for (int j = 0; j < 4; j++) {
            const int col  = n_base + j * 16 + frow;
            const int row0 = m_base + i * 16 + quad * 4;
            if (EPI == 0) {
                const float bb = bias[col];
                u16* C = (u16*)Cv + z * batchC;
#pragma unroll
                for (int r = 0; r < 4; r++)
                    C[(long)(row0 + r) * ldc + col] = f2bf(acc[i][j][r] + bb);
            } else if (EPI == 1) {
                u16* C = (u16*)Cv + z * batchC;
#pragma unroll
                for (int r = 0; r < 4; r++)
                    C[(long)(row0 + r) * ldc + col] = f2bf(acc[i][j][r] * scale);
            } else {
                float* C = (float*)Cv + z * batchC;
#pragma unroll
                for (int r = 0; r < 4; r++)
                    C[(long)(row0 + r) * ldc + col] = acc[i][j][r];
            }
        }
    }
}

// ---------- rowwise softmax, in place, bf16 -> bf16 (fp32 internal) ----------
__global__ __launch_bounds__(256) void softmax_kernel(u16* __restrict__ Sc) {
    u16* row = Sc + (size_t)blockIdx.x * 4096;
    const int t = threadIdx.x;
    __shared__ float sm[4], ss[4];

    u16x8 r0 = *(const u16x8*)&row[t * 8];
    u16x8 r1 = *(const u16x8*)&row[(t + 256) * 8];
    float v[16];
#pragma unroll
    for (int i = 0; i < 8; i++) { v[i] = bf2f(r0[i]); v[8 + i] = bf2f(r1[i]); }

    float m = -1e30f;
#pragma unroll
    for (int i = 0; i < 16; i++) m = fmaxf(m, v[i]);
#pragma unroll
    for (int off = 1; off < 64; off <<= 1) m = fmaxf(m, __shfl_xor(m, off));
    if ((t & 63) == 0) sm[t >> 6] = m;
    __syncthreads();
    m = fmaxf(fmaxf(sm[0], sm[1]), fmaxf(sm[2], sm[3]));

    float s = 0.f;
#pragma unroll
    for (int i = 0; i < 16; i++) { v[i] = __expf(v[i] - m); s += v[i]; }
#pragma unroll
    for (int off = 1; off < 64; off <<= 1) s += __shfl_xor(s, off);
    if ((t & 63) == 0) ss[t >> 6] = s;
    __syncthreads();
    s = ss[0] + ss[1] + ss[2] + ss[3];
    const float inv = 1.0f / s;

    u16x8 o0, o1;
#pragma unroll
    for (int i = 0; i < 8; i++) { o0[i] = f2bf(v[i] * inv); o1[i] = f2bf(v[8 + i] * inv); }
    *(u16x8*)&row[t * 8] = o0;
    *(u16x8*)&row[(t + 256) * 8] = o1;
}

extern "C" void kernel_launch(void* const* d_in, const int* in_sizes, int n_in,
                              void* d_out, int out_size, void* d_ws, size_t ws_size,
                              hipStream_t stream) {
    const float* x  = (const float*)d_in[0];
    const float* Wq = (const float*)d_in[1];
    const float* bq = (const float*)d_in[2];
    const float* Wk = (const float*)d_in[3];
    const float* bk = (const float*)d_in[4];
    const float* Wv = (const float*)d_in[5];
    const float* bv = (const float*)d_in[6];
    float* out = (float*)d_out;

    // B=4, S=4096, D=768; M = 16384 tokens.
    uint8_t* ws = (uint8_t*)d_ws;
    u16* xb  = (u16*)(ws + 0);           // 25,165,824 B (aliased by Vt after projections)
    u16* Vt  = (u16*)(ws + 0);
    u16* wqb = (u16*)(ws + 25165824);
    u16* wkb = (u16*)(ws + 26345472);
    u16* wvb = (u16*)(ws + 27525120);
    u16* Qb  = (u16*)(ws + 28704768);
    u16* Kb  = (u16*)(ws + 53870592);
    u16* Vb  = (u16*)(ws + 79036416);
    u16* Sc  = (u16*)(ws + 104202240);   // 134,217,728 B -> total ~227 MiB

    // 1) casts
    cast_bf16_kernel<<<12288, 256, 0, stream>>>(x, xb, 3145728);
    cast_bf16_kernel<<<576, 256, 0, stream>>>(Wq, wqb, 147456);
    cast_bf16_kernel<<<576, 256, 0, stream>>>(Wk, wkb, 147456);
    cast_bf16_kernel<<<576, 256, 0, stream>>>(Wv, wvb, 147456);

    // 2) projections: [16384,768] x [768,768]^T + bias -> bf16
    dim3 gp(6, 128, 1);
    gemm_bt_kernel<0><<<gp, 256, 0, stream>>>(xb, wqb, Qb, bq, 1.f, 768, 768, 768, 768, 0, 0, 0);
    gemm_bt_kernel<0><<<gp, 256, 0, stream>>>(xb, wkb, Kb, bk, 1.f, 768, 768, 768, 768, 0, 0, 0);
    gemm_bt_kernel<0><<<gp, 256, 0, stream>>>(xb, wvb, Vb, bv, 1.f, 768, 768, 768, 768, 0, 0, 0);

    // 3) V transpose per batch: Vt[e][s]
    transpose_bf16_kernel<<<dim3(24, 128, 4), 256, 0, stream>>>(Vb, Vt);

    // 4) scores: S = scale * Q K^T  (per batch, 4096x4096, K=768), bf16
    dim3 g1(32, 32, 4);
    gemm_bt_kernel<1><<<g1, 256, 0, stream>>>(Qb, Kb, Sc, nullptr, 0.03608439182435161f,
                                              768, 768, 768, 4096,
                                              (long)4096 * 768, (long)4096 * 768, (long)4096 * 4096);

    // 5) softmax rows (in place)
    softmax_kernel<<<16384, 256, 0, stream>>>(Sc);

    // 6) O = P Vt^T -> fp32 out  (per batch, M=4096, N=768, K=4096)
    dim3 g2(6, 32, 4);
    gemm_bt_kernel<2><<<g2, 256, 0, stream>>>(Sc, Vt, out, nullptr, 1.f,
                                              4096, 4096, 4096, 768,
                                              (long)4096 * 4096, (long)768 * 4096, (long)4096 * 768);
}

// Round 2
// 504.392 us; speedup vs baseline: 1.1554x; 1.1554x over previous
//
#include <hip/hip_runtime.h>
#include <stdint.h>

typedef unsigned short u16;
typedef __attribute__((ext_vector_type(8))) short    bf16x8;   // 8 bf16 in 4 VGPRs
typedef __attribute__((ext_vector_type(4))) float    f32x4;

// ---------- helpers ----------
__device__ __forceinline__ u16 f2bf(float f) {           // fp32 -> bf16, round-nearest-even
    unsigned u = __float_as_uint(f);
    u = (u + 0x7fffu + ((u >> 16) & 1u)) >> 16;
    return (u16)u;
}
// async global->LDS, 16 bytes per lane (global_load_lds_dwordx4)
__device__ __forceinline__ void gload16(const u16* g, u16* l) {
    __builtin_amdgcn_global_load_lds((const __attribute__((address_space(1))) void*)g,
                                     (__attribute__((address_space(3))) void*)l,
                                     16, 0, 0);
}

// ---------- fp32 -> bf16 cast (vectorized) ----------
__global__ __launch_bounds__(256) void cast_bf16_kernel(const float* __restrict__ in,
                                                        u16* __restrict__ out, int n4) {
    int i = blockIdx.x * 256 + threadIdx.x;
    if (i < n4) {
        float4 f = ((const float4*)in)[i];
        ushort4 o;
        o.x = f2bf(f.x); o.y = f2bf(f.y); o.z = f2bf(f.z); o.w = f2bf(f.w);
        ((ushort4*)out)[i] = o;
    }
}

// cast the three weight matrices into one concatenated [2304][768] bf16 buffer
__global__ __launch_bounds__(256) void cast3_bf16_kernel(const float* __restrict__ w0,
                                                         const float* __restrict__ w1,
                                                         const float* __restrict__ w2,
                                                         u16* __restrict__ out) {
    const float* src = (blockIdx.y == 0) ? w0 : (blockIdx.y == 1) ? w1 : w2;
    int i = blockIdx.x * 256 + threadIdx.x;          // 576*256 = 147456 = 768*768/4
    float4 f = ((const float4*)src)[i];
    ushort4 o;
    o.x = f2bf(f.x); o.y = f2bf(f.y); o.z = f2bf(f.z); o.w = f2bf(f.w);
    ((ushort4*)out)[(size_t)blockIdx.y * 147456 + i] = o;
}

// ---------- bf16 32x32-tiled transpose: Vt[b][e][s] = V[b][s][e] (ld_in=2304) ----------
// also zeroes the rowsum buffer (it aliases the dead weight buffer; runs after proj GEMM)
__global__ __launch_bounds__(256) void transpose_bf16_kernel(const u16* __restrict__ V,
                                                             u16* __restrict__ Vt,
                                                             float* __restrict__ rsum) {
    __shared__ u16 tile[32][33];
    const int t = threadIdx.x;
    if (blockIdx.x == 0 && blockIdx.z == 0) {
        int idx = blockIdx.y * 256 + t;
        if (idx < 16384) rsum[idx] = 0.f;
    }
    const size_t z = blockIdx.z;
    const u16* Vb  = V  + z * (size_t)4096 * 2304;
    u16*       Vtb = Vt + z * (size_t)768 * 4096;
    const int c0 = blockIdx.x * 32;           // D (col) tile
    const int r0 = blockIdx.y * 32;           // S (row) tile
    const int lr = t >> 3;                    // 0..31
    const int lc = (t & 7) * 4;               // 0..28
    ushort4 in = *(const ushort4*)&Vb[(size_t)(r0 + lr) * 2304 + c0 + lc];
    tile[lr][lc + 0] = in.x; tile[lr][lc + 1] = in.y;
    tile[lr][lc + 2] = in.z; tile[lr][lc + 3] = in.w;
    __syncthreads();
    ushort4 o;
    o.x = tile[lc + 0][lr]; o.y = tile[lc + 1][lr];
    o.z = tile[lc + 2][lr]; o.w = tile[lc + 3][lr];
    *(ushort4*)&Vtb[(size_t)(c0 + lr) * 4096 + r0 + lc] = o;
}

// ---------- m97-style GEMM: C[m][n] = sum_k A[m][k]*B[n][k]  (both row-major bf16) ----------
// 128x128 block tile, BK=32, 4 waves in 2x2, each wave 64x64 via 4x4 MFMA 16x16x32.
// EPI: 0 = +bias[col] (b0/b1/b2 selected per 768-col segment), bf16 out   (QKV projection)
//      1 = exp(acc*scale), bf16 out, atomicAdd row sums into rs            (QK^T -> E)
//      2 = acc * (1/rs[row]), fp32 out                                     (E*Vt -> O)
// SWIZ: 1 = 1D grid of 768, decoded so the 6 N-blocks sharing an M-strip land on one XCD.
template <int EPI, int SWIZ>
__global__ __launch_bounds__(256) void gemm_bt_kernel(
        const u16* __restrict__ A, const u16* __restrict__ B, void* __restrict__ Cv,
        const float* __restrict__ b0, const float* __restrict__ b1, const float* __restrict__ b2,
        float* __restrict__ rs, float scale, int K,
        int lda, int ldb, int ldc, long batchA, long batchB, long batchC) {
    __shared__ __align__(16) u16 As[128 * 32];
    __shared__ __align__(16) u16 Bs[128 * 32];

    int bx, by, bz;
    if (SWIZ) {   // grid = 768 1D: XCD c gets lin%8==c; x varies fastest within an XCD stream
        const int lin = blockIdx.x;
        const int c = lin & 7, p = lin >> 3;      // p in [0,96)
        bx = p % 6;
        const int strip = 16 * c + p / 6;         // [0,128)
        by = strip & 31; bz = strip >> 5;
    } else {
        bx = blockIdx.x; by = blockIdx.y; bz = blockIdx.z;
    }

    const int t = threadIdx.x;
    const long z = bz;
    const u16* Ab = A + z * batchA + (long)by * 128 * lda;
    const u16* Bb = B + z * batchB + (long)bx * 128 * ldb;

    const int lane = t & 63;
    const int wave = t >> 6;
    const int wm = wave >> 1, wn = wave & 1;      // 2x2 wave grid (64x64 each)
    const int quad = lane >> 4;
    const int frow = lane & 15;

    f32x4 acc[4][4];
#pragma unroll
    for (int i = 0; i < 4; i++)
#pragma unroll
        for (int j = 0; j < 4; j++)
#pragma unroll
            for (int e = 0; e < 4; e++) acc[i][j][e] = 0.f;

    // staging: 512 chunks of 16B per 8KB tile; thread t does chunks t and t+256
    const int c0 = t, c1 = t + 256;
    const int ar0 = c0 >> 2, as0 = (c0 & 3) * 8;
    const int ar1 = c1 >> 2, as1 = (c1 & 3) * 8;

    for (int kt = 0; kt < K; kt += 32) {
        gload16(Ab + (long)ar0 * lda + kt + as0, &As[c0 * 8]);
        gload16(Ab + (long)ar1 * lda + kt + as1, &As[c1 * 8]);
        gload16(Bb + (long)ar0 * ldb + kt + as0, &Bs[c0 * 8]);
        gload16(Bb + (long)ar1 * ldb + kt + as1, &Bs[c1 * 8]);
        __syncthreads();

        bf16x8 af[4], bfr[4];
#pragma unroll
        for (int i = 0; i < 4; i++) {
            af[i]  = *(const bf16x8*)&As[(wm * 64 + i * 16 + frow) * 32 + quad * 8];
            bfr[i] = *(const bf16x8*)&Bs[(wn * 64 + i * 16 + frow) * 32 + quad * 8];
        }
#pragma unroll
        for (int i = 0; i < 4; i++)
#pragma unroll
            for (int j = 0; j < 4; j++)
                acc[i][j] = __builtin_amdgcn_mfma_f32_16x16x32_bf16(af[i], bfr[j], acc[i][j], 0, 0, 0);
        __syncthreads();
    }

    // epilogue: C/D layout col = lane&15 (n), row = quad*4 + reg (m)  [m89-verified]
    const int m_base = by * 128 + wm * 64;
    const int n_base = bx * 128 + wn * 64;

    float rowpart[4][4];
    if (EPI == 1) {
#pragma unroll
        for (int i = 0; i < 4; i++)
#pragma unroll
            for (int r = 0; r < 4; r++) rowpart[i][r] = 0.f;
    }

#pragma unroll
    for (int i = 0; i < 4; i++) {
#pragma unroll
        for (int j = 0; j < 4; j++) {
            const int col  = n_base + j * 16 + frow;
            const int row0 = m_base + i * 16 + quad * 4;
            if (EPI == 0) {
                const int seg = n_base / 768;     // block-uniform (128 | 768)
                const float* bp = ((seg == 0) ? b0 : (seg == 1) ? b1 : b2) - (long)seg * 768;
                const float bb = bp[col];
                u16* C = (u16*)Cv + z * batchC;
#pragma unroll
                for (int r = 0; r < 4; r++)
                    C[(long)(row0 + r) * ldc + col] = f2bf(acc[i][j][r] + bb);
            } else if (EPI == 1) {
                u16* C = (u16*)Cv + z * batchC;
#pragma unroll
                for (int r = 0; r < 4; r++) {
                    float e = __expf(acc[i][j][r] * scale);
                    C[(long)(row0 + r) * ldc + col] = f2bf(e);
                    rowpart[i][r] += e;
                }
            } else {
                float* C = (float*)Cv + z * batchC;
#pragma unroll
                for (int r = 0; r < 4; r++) {
                    const float inv = 1.0f / rs[z * 4096 + row0 + r];
                    C[(long)(row0 + r) * ldc + col] = acc[i][j][r] * inv;
                }
            }
        }
    }

    if (EPI == 1) {
        // reduce each row's partial over the 16 frow lanes, then one atomic per row
#pragma unroll
        for (int i = 0; i < 4; i++)
#pragma unroll
            for (int r = 0; r < 4; r++) {
                float v = rowpart[i][r];
                v += __shfl_xor(v, 1); v += __shfl_xor(v, 2);
                v += __shfl_xor(v, 4); v += __shfl_xor(v, 8);
                if (frow == 0)
                    atomicAdd(&rs[z * 4096 + m_base + i * 16 + quad * 4 + r], v);
            }
    }
}

extern "C" void kernel_launch(void* const* d_in, const int* in_sizes, int n_in,
                              void* d_out, int out_size, void* d_ws, size_t ws_size,
                              hipStream_t stream) {
    const float* x  = (const float*)d_in[0];
    const float* Wq = (const float*)d_in[1];
    const float* bq = (const float*)d_in[2];
    const float* Wk = (const float*)d_in[3];
    const float* bk = (const float*)d_in[4];
    const float* Wv = (const float*)d_in[5];
    const float* bv = (const float*)d_in[6];
    float* out = (float*)d_out;

    // B=4, S=4096, D=768; 16384 tokens. Workspace layout (total 238,419,968 B):
    //  @0          : xb bf16 [16384][768]      (25,165,824)  -- dead after proj; Vt reuses it
    //  @25,165,824 : QKV bf16 [16384][2304]    (75,497,472)
    //  @100,663,296: E bf16 [4][4096][4096]    (134,217,728)
    //  @234,881,024: Wqkv bf16 [2304][768]     (3,538,944)   -- dead after proj;
    //                 rowsum fp32[16384] (65,536) aliases its head, zeroed in transpose
    uint8_t* ws = (uint8_t*)d_ws;
    u16*   xb   = (u16*)(ws + 0);
    u16*   Vt   = (u16*)(ws + 0);
    u16*   QKV  = (u16*)(ws + 25165824);
    u16*   E    = (u16*)(ws + 100663296);
    u16*   Wqkv = (u16*)(ws + 234881024);
    float* rsum = (float*)(ws + 234881024);

    // 1) casts
    cast_bf16_kernel<<<12288, 256, 0, stream>>>(x, xb, 3145728);
    cast3_bf16_kernel<<<dim3(576, 3), 256, 0, stream>>>(Wq, Wk, Wv, Wqkv);

    // 2) fused QKV projection: [16384,768] x [2304,768]^T + bias -> QKV bf16 (ldc 2304)
    gemm_bt_kernel<0, 0><<<dim3(18, 128, 1), 256, 0, stream>>>(
        xb, Wqkv, QKV, bq, bk, bv, nullptr, 1.f, 768, 768, 768, 2304, 0, 0, 0);

    // 3) V transpose per batch (V = QKV cols [1536,2304), ld 2304) -> Vt[e][s]; zero rowsum
    transpose_bf16_kernel<<<dim3(24, 128, 4), 256, 0, stream>>>(QKV + 1536, Vt, rsum);

    // 4) E = exp(scale * Q K^T) (per batch, 4096x4096, K=768) + rowsum atomics
    gemm_bt_kernel<1, 0><<<dim3(32, 32, 4), 256, 0, stream>>>(
        QKV, QKV + 768, E, nullptr, nullptr, nullptr, rsum, 0.036084391824351615f,
        768, 2304, 2304, 4096, (long)4096 * 2304, (long)4096 * 2304, (long)4096 * 4096);

    // 5) O = (E Vt^T) / rowsum -> fp32 out (per batch, M=4096, N=768, K=4096), XCD-swizzled
    gemm_bt_kernel<2, 1><<<768, 256, 0, stream>>>(
        E, Vt, out, nullptr, nullptr, nullptr, rsum, 1.f,
        4096, 4096, 4096, 768, (long)4096 * 4096, (long)768 * 4096, (long)4096 * 768);
}

// Round 3
// 484.933 us; speedup vs baseline: 1.2017x; 1.0401x over previous
//
#include <hip/hip_runtime.h>
#include <stdint.h>

typedef unsigned short u16;
typedef __attribute__((ext_vector_type(8))) short    bf16x8;   // 8 bf16 in 4 VGPRs
typedef __attribute__((ext_vector_type(4))) float    f32x4;

// ---------- helpers ----------
__device__ __forceinline__ u16 f2bf(float f) {           // fp32 -> bf16, round-nearest-even
    unsigned u = __float_as_uint(f);
    u = (u + 0x7fffu + ((u >> 16) & 1u)) >> 16;
    return (u16)u;
}
// async global->LDS, 16 bytes per lane (global_load_lds_dwordx4)
__device__ __forceinline__ void gload16(const u16* g, u16* l) {
    __builtin_amdgcn_global_load_lds((const __attribute__((address_space(1))) void*)g,
                                     (__attribute__((address_space(3))) void*)l,
                                     16, 0, 0);
}

// ---------- fp32 -> bf16 cast (vectorized) ----------
__global__ __launch_bounds__(256) void cast_bf16_kernel(const float* __restrict__ in,
                                                        u16* __restrict__ out, int n4) {
    int i = blockIdx.x * 256 + threadIdx.x;
    if (i < n4) {
        float4 f = ((const float4*)in)[i];
        ushort4 o;
        o.x = f2bf(f.x); o.y = f2bf(f.y); o.z = f2bf(f.z); o.w = f2bf(f.w);
        ((ushort4*)out)[i] = o;
    }
}

// cast the three weight matrices into one concatenated [2304][768] bf16 buffer
__global__ __launch_bounds__(256) void cast3_bf16_kernel(const float* __restrict__ w0,
                                                         const float* __restrict__ w1,
                                                         const float* __restrict__ w2,
                                                         u16* __restrict__ out) {
    const float* src = (blockIdx.y == 0) ? w0 : (blockIdx.y == 1) ? w1 : w2;
    int i = blockIdx.x * 256 + threadIdx.x;          // 576*256 = 147456 = 768*768/4
    float4 f = ((const float4*)src)[i];
    ushort4 o;
    o.x = f2bf(f.x); o.y = f2bf(f.y); o.z = f2bf(f.z); o.w = f2bf(f.w);
    ((ushort4*)out)[(size_t)blockIdx.y * 147456 + i] = o;
}

// ---------- bf16 32x32-tiled transpose: Vt[b][e][s] = V[b][s][e] (ld_in=2304) ----------
// also zeroes the rowsum buffer (it aliases the dead weight buffer; runs after proj GEMM)
__global__ __launch_bounds__(256) void transpose_bf16_kernel(const u16* __restrict__ V,
                                                             u16* __restrict__ Vt,
                                                             float* __restrict__ rsum) {
    __shared__ u16 tile[32][33];
    const int t = threadIdx.x;
    if (blockIdx.x == 0 && blockIdx.z == 0) {
        int idx = blockIdx.y * 256 + t;
        if (idx < 16384) rsum[idx] = 0.f;
    }
    const size_t z = blockIdx.z;
    const u16* Vb  = V  + z * (size_t)4096 * 2304;
    u16*       Vtb = Vt + z * (size_t)768 * 4096;
    const int c0 = blockIdx.x * 32;           // D (col) tile
    const int r0 = blockIdx.y * 32;           // S (row) tile
    const int lr = t >> 3;                    // 0..31
    const int lc = (t & 7) * 4;               // 0..28
    ushort4 in = *(const ushort4*)&Vb[(size_t)(r0 + lr) * 2304 + c0 + lc];
    tile[lr][lc + 0] = in.x; tile[lr][lc + 1] = in.y;
    tile[lr][lc + 2] = in.z; tile[lr][lc + 3] = in.w;
    __syncthreads();
    ushort4 o;
    o.x = tile[lc + 0][lr]; o.y = tile[lc + 1][lr];
    o.z = tile[lc + 2][lr]; o.w = tile[lc + 3][lr];
    *(ushort4*)&Vtb[(size_t)(c0 + lr) * 4096 + r0 + lc] = o;
}

// ---------- m97-style GEMM: C[m][n] = sum_k A[m][k]*B[n][k]  (both row-major bf16) ----------
// 128x128 block tile, BK=32, 4 waves in 2x2, each wave 64x64 via 4x4 MFMA 16x16x32.
// EPI: 0 = +bias[col] (b0/b1/b2 per 768-col segment), bf16 out            (QKV projection)
//      1 = exp2(acc*s2), bf16 out, atomicAdd row sums into rs             (QK^T -> E)
//      2 = acc * (1/rs[row]), fp32 out                                    (E*Vt -> O)
// Grid is 1D = NGRID, XCD-swizzled: lin%8 = XCD, bx fastest within an XCD's strip so
// blocks sharing an A-strip (and B panel) land on the same XCD's L2.
template <int EPI, int NBX, int NGRID, int NBY>
__global__ __launch_bounds__(256, 4) void gemm_bt_kernel(
        const u16* __restrict__ A, const u16* __restrict__ B, void* __restrict__ Cv,
        const float* __restrict__ b0, const float* __restrict__ b1, const float* __restrict__ b2,
        float* __restrict__ rs, float s2, int K,
        int lda, int ldb, int ldc, long batchA, long batchB, long batchC) {
    __shared__ __align__(16) u16 As[128 * 32];
    __shared__ __align__(16) u16 Bs[128 * 32];

    constexpr int SPX = NGRID / (8 * NBX);        // strips per XCD
    const int lin = blockIdx.x;
    const int c = lin & 7, p = lin >> 3;
    const int bx = p % NBX;
    const int strip = c * SPX + p / NBX;
    const int by = strip % NBY;
    const int bz = strip / NBY;

    const int t = threadIdx.x;
    const long z = bz;
    const u16* Ab = A + z * batchA + (long)by * 128 * lda;
    const u16* Bb = B + z * batchB + (long)bx * 128 * ldb;

    const int lane = t & 63;
    const int wave = t >> 6;
    const int wm = wave >> 1, wn = wave & 1;      // 2x2 wave grid (64x64 each)
    const int quad = lane >> 4;
    const int frow = lane & 15;

    f32x4 acc[4][4];
#pragma unroll
    for (int i = 0; i < 4; i++)
#pragma unroll
        for (int j = 0; j < 4; j++)
#pragma unroll
            for (int e = 0; e < 4; e++) acc[i][j][e] = 0.f;

    // staging: 512 chunks of 16B per 8KB tile; thread t does chunks t and t+256
    const int c0 = t, c1 = t + 256;
    const int ar0 = c0 >> 2, as0 = (c0 & 3) * 8;
    const int ar1 = c1 >> 2, as1 = (c1 & 3) * 8;

    for (int kt = 0; kt < K; kt += 32) {
        gload16(Ab + (long)ar0 * lda + kt + as0, &As[c0 * 8]);
        gload16(Ab + (long)ar1 * lda + kt + as1, &As[c1 * 8]);
        gload16(Bb + (long)ar0 * ldb + kt + as0, &Bs[c0 * 8]);
        gload16(Bb + (long)ar1 * ldb + kt + as1, &Bs[c1 * 8]);
        __syncthreads();

        // keep only bfr[4] + one af live (fewer VGPRs -> 4 blocks/CU)
        bf16x8 bfr[4];
#pragma unroll
        for (int j = 0; j < 4; j++)
            bfr[j] = *(const bf16x8*)&Bs[(wn * 64 + j * 16 + frow) * 32 + quad * 8];
#pragma unroll
        for (int i = 0; i < 4; i++) {
            bf16x8 af = *(const bf16x8*)&As[(wm * 64 + i * 16 + frow) * 32 + quad * 8];
#pragma unroll
            for (int j = 0; j < 4; j++)
                acc[i][j] = __builtin_amdgcn_mfma_f32_16x16x32_bf16(af, bfr[j], acc[i][j], 0, 0, 0);
        }
        __syncthreads();
    }

    // epilogue: C/D layout col = lane&15 (n), row = quad*4 + reg (m)  [m89-verified]
    const int m_base = by * 128 + wm * 64;
    const int n_base = bx * 128 + wn * 64;

    if (EPI == 0) {
        const int seg = n_base / 768;             // block-uniform (128 | 768)
        const float* bp = (seg == 0) ? b0 : (seg == 1) ? b1 : b2;
        u16* C = (u16*)Cv + z * batchC;
#pragma unroll
        for (int j = 0; j < 4; j++) {
            const int col = n_base + j * 16 + frow;
            const float bb = bp[col - seg * 768];
#pragma unroll
            for (int i = 0; i < 4; i++) {
                const int row0 = m_base + i * 16 + quad * 4;
#pragma unroll
                for (int r = 0; r < 4; r++)
                    C[(long)(row0 + r) * ldc + col] = f2bf(acc[i][j][r] + bb);
            }
        }
    } else if (EPI == 1) {
        u16* C = (u16*)Cv + z * batchC;
        float rowpart[4][4];
#pragma unroll
        for (int i = 0; i < 4; i++)
#pragma unroll
            for (int r = 0; r < 4; r++) rowpart[i][r] = 0.f;
#pragma unroll
        for (int i = 0; i < 4; i++) {
            const int row0 = m_base + i * 16 + quad * 4;
#pragma unroll
            for (int j = 0; j < 4; j++) {
                const int col = n_base + j * 16 + frow;
#pragma unroll
                for (int r = 0; r < 4; r++) {
                    float e = exp2f(acc[i][j][r] * s2);
                    C[(long)(row0 + r) * ldc + col] = f2bf(e);
                    rowpart[i][r] += e;
                }
            }
        }
        // reduce each row's partial over the 16 frow lanes, then one atomic per row
#pragma unroll
        for (int i = 0; i < 4; i++)
#pragma unroll
            for (int r = 0; r < 4; r++) {
                float v = rowpart[i][r];
                v += __shfl_xor(v, 1); v += __shfl_xor(v, 2);
                v += __shfl_xor(v, 4); v += __shfl_xor(v, 8);
                if (frow == 0)
                    atomicAdd(&rs[z * 4096 + m_base + i * 16 + quad * 4 + r], v);
            }
    } else {
        float* C = (float*)Cv + z * batchC;
#pragma unroll
        for (int i = 0; i < 4; i++) {
            const int row0 = m_base + i * 16 + quad * 4;
            float inv[4];
#pragma unroll
            for (int r = 0; r < 4; r++) inv[r] = 1.0f / rs[z * 4096 + row0 + r];
#pragma unroll
            for (int j = 0; j < 4; j++) {
                const int col = n_base + j * 16 + frow;
#pragma unroll
                for (int r = 0; r < 4; r++)
                    C[(long)(row0 + r) * ldc + col] = acc[i][j][r] * inv[r];
            }
        }
    }
}

extern "C" void kernel_launch(void* const* d_in, const int* in_sizes, int n_in,
                              void* d_out, int out_size, void* d_ws, size_t ws_size,
                              hipStream_t stream) {
    const float* x  = (const float*)d_in[0];
    const float* Wq = (const float*)d_in[1];
    const float* bq = (const float*)d_in[2];
    const float* Wk = (const float*)d_in[3];
    const float* bk = (const float*)d_in[4];
    const float* Wv = (const float*)d_in[5];
    const float* bv = (const float*)d_in[6];
    float* out = (float*)d_out;

    // B=4, S=4096, D=768; 16384 tokens. Workspace layout (total 238,419,968 B):
    //  @0          : xb bf16 [16384][768]      (25,165,824)  -- dead after proj; Vt reuses it
    //  @25,165,824 : QKV bf16 [16384][2304]    (75,497,472)
    //  @100,663,296: E bf16 [4][4096][4096]    (134,217,728)
    //  @234,881,024: Wqkv bf16 [2304][768]     (3,538,944)   -- dead after proj;
    //                 rowsum fp32[16384] (65,536) aliases its head, zeroed in transpose
    uint8_t* ws = (uint8_t*)d_ws;
    u16*   xb   = (u16*)(ws + 0);
    u16*   Vt   = (u16*)(ws + 0);
    u16*   QKV  = (u16*)(ws + 25165824);
    u16*   E    = (u16*)(ws + 100663296);
    u16*   Wqkv = (u16*)(ws + 234881024);
    float* rsum = (float*)(ws + 234881024);

    // 1) casts
    cast_bf16_kernel<<<12288, 256, 0, stream>>>(x, xb, 3145728);
    cast3_bf16_kernel<<<dim3(576, 3), 256, 0, stream>>>(Wq, Wk, Wv, Wqkv);

    // 2) fused QKV projection: [16384,768] x [2304,768]^T + bias -> QKV bf16 (ldc 2304)
    //    grid 2304 = 8 XCDs x (18 bx x 16 strips); weight panel (3.5 MB) L2-resident per XCD
    gemm_bt_kernel<0, 18, 2304, 128><<<2304, 256, 0, stream>>>(
        xb, Wqkv, QKV, bq, bk, bv, nullptr, 0.f, 768, 768, 768, 2304, 0, 0, 0);

    // 3) V transpose per batch (V = QKV cols [1536,2304), ld 2304) -> Vt[e][s]; zero rowsum
    transpose_bf16_kernel<<<dim3(24, 128, 4), 256, 0, stream>>>(QKV + 1536, Vt, rsum);

    // 4) E = exp(scale * Q K^T) (per batch, 4096x4096, K=768) + rowsum atomics
    //    s2 = (1/sqrt(768)) * log2(e); grid 4096 = 8 x (32 bx x 16 strips)
    gemm_bt_kernel<1, 32, 4096, 32><<<4096, 256, 0, stream>>>(
        QKV, QKV + 768, E, nullptr, nullptr, nullptr, rsum, 0.05205954822032348f,
        768, 2304, 2304, 4096, (long)4096 * 2304, (long)4096 * 2304, (long)4096 * 4096);

    // 5) O = (E Vt^T) / rowsum -> fp32 out (per batch, M=4096, N=768, K=4096)
    gemm_bt_kernel<2, 6, 768, 32><<<768, 256, 0, stream>>>(
        E, Vt, out, nullptr, nullptr, nullptr, rsum, 0.f,
        4096, 4096, 4096, 768, (long)4096 * 4096, (long)768 * 4096, (long)4096 * 768);
}

// Round 4
// 442.438 us; speedup vs baseline: 1.3171x; 1.0960x over previous
//
#include <hip/hip_runtime.h>
#include <stdint.h>

typedef unsigned short u16;
typedef __attribute__((ext_vector_type(8))) short    bf16x8;   // 8 bf16 in 4 VGPRs
typedef __attribute__((ext_vector_type(4))) float    f32x4;

// ---------- helpers ----------
__device__ __forceinline__ u16 f2bf(float f) {           // fp32 -> bf16, round-nearest-even
    unsigned u = __float_as_uint(f);
    u = (u + 0x7fffu + ((u >> 16) & 1u)) >> 16;
    return (u16)u;
}
// async global->LDS, 16 bytes per lane (global_load_lds_dwordx4)
__device__ __forceinline__ void gload16(const u16* g, u16* l) {
    __builtin_amdgcn_global_load_lds((const __attribute__((address_space(1))) void*)g,
                                     (__attribute__((address_space(3))) void*)l,
                                     16, 0, 0);
}

// ---------- fp32 -> bf16 cast (vectorized) ----------
__global__ __launch_bounds__(256) void cast_bf16_kernel(const float* __restrict__ in,
                                                        u16* __restrict__ out, int n4) {
    int i = blockIdx.x * 256 + threadIdx.x;
    if (i < n4) {
        float4 f = ((const float4*)in)[i];
        ushort4 o;
        o.x = f2bf(f.x); o.y = f2bf(f.y); o.z = f2bf(f.z); o.w = f2bf(f.w);
        ((ushort4*)out)[i] = o;
    }
}

// cast the three weight matrices into one concatenated [2304][768] bf16 buffer
__global__ __launch_bounds__(256) void cast3_bf16_kernel(const float* __restrict__ w0,
                                                         const float* __restrict__ w1,
                                                         const float* __restrict__ w2,
                                                         u16* __restrict__ out) {
    const float* src = (blockIdx.y == 0) ? w0 : (blockIdx.y == 1) ? w1 : w2;
    int i = blockIdx.x * 256 + threadIdx.x;          // 576*256 = 147456 = 768*768/4
    float4 f = ((const float4*)src)[i];
    ushort4 o;
    o.x = f2bf(f.x); o.y = f2bf(f.y); o.z = f2bf(f.z); o.w = f2bf(f.w);
    ((ushort4*)out)[(size_t)blockIdx.y * 147456 + i] = o;
}

// ---------- bf16 32x32-tiled transpose: Vt[b][e][s] = V[b][s][e] (ld_in=2304) ----------
// also zeroes the rowsum buffer (it aliases the dead weight buffer; runs after proj GEMM)
__global__ __launch_bounds__(256) void transpose_bf16_kernel(const u16* __restrict__ V,
                                                             u16* __restrict__ Vt,
                                                             float* __restrict__ rsum) {
    __shared__ u16 tile[32][33];
    const int t = threadIdx.x;
    if (blockIdx.x == 0 && blockIdx.z == 0) {
        int idx = blockIdx.y * 256 + t;
        if (idx < 16384) rsum[idx] = 0.f;
    }
    const size_t z = blockIdx.z;
    const u16* Vb  = V  + z * (size_t)4096 * 2304;
    u16*       Vtb = Vt + z * (size_t)768 * 4096;
    const int c0 = blockIdx.x * 32;           // D (col) tile
    const int r0 = blockIdx.y * 32;           // S (row) tile
    const int lr = t >> 3;                    // 0..31
    const int lc = (t & 7) * 4;               // 0..28
    ushort4 in = *(const ushort4*)&Vb[(size_t)(r0 + lr) * 2304 + c0 + lc];
    tile[lr][lc + 0] = in.x; tile[lr][lc + 1] = in.y;
    tile[lr][lc + 2] = in.z; tile[lr][lc + 3] = in.w;
    __syncthreads();
    ushort4 o;
    o.x = tile[lc + 0][lr]; o.y = tile[lc + 1][lr];
    o.z = tile[lc + 2][lr]; o.w = tile[lc + 3][lr];
    *(ushort4*)&Vtb[(size_t)(c0 + lr) * 4096 + r0 + lc] = o;
}

// ---------- m97-style GEMM, BK=64: C[m][n] = sum_k A[m][k]*B[n][k] (row-major bf16) ----------
// 128x128 block tile, BK=64 (32 KB LDS, 4 blocks/CU, HALF the barriers of BK=32),
// 4 waves in 2x2, each wave 64x64 via 4x4 MFMA 16x16x32, 2 k-chunks per tile.
// LDS XOR swizzle: chunk (r,c) holds global chunk (r, c^(r&7)) -- keeps the
// global_load_lds dest contiguous (uniform+lane*16) while breaking the 32-bank
// row-stride alias (conflict groups of 8, same as the proven BK=32 layout).
// EPI: 0 = +bias[col] (b0/b1/b2 per 768-col segment), bf16 out            (QKV projection)
//      1 = exp2(acc*s2), bf16 out, atomicAdd row sums into rs             (QK^T -> E)
//      2 = acc * (1/rs[row]), fp32 out                                    (E*Vt -> O)
// Grid is 1D = NGRID, XCD-swizzled: lin%8 = XCD, bx fastest within an XCD's strip.
template <int EPI, int NBX, int NGRID, int NBY>
__global__ __launch_bounds__(256, 4) void gemm_bt_kernel(
        const u16* __restrict__ A, const u16* __restrict__ B, void* __restrict__ Cv,
        const float* __restrict__ b0, const float* __restrict__ b1, const float* __restrict__ b2,
        float* __restrict__ rs, float s2, int K,
        int lda, int ldb, int ldc, long batchA, long batchB, long batchC) {
    __shared__ __align__(16) u16 As[128 * 64];
    __shared__ __align__(16) u16 Bs[128 * 64];

    constexpr int SPX = NGRID / (8 * NBX);        // strips per XCD
    const int lin = blockIdx.x;
    const int c = lin & 7, p = lin >> 3;
    const int bx = p % NBX;
    const int strip = c * SPX + p / NBX;
    const int by = strip % NBY;
    const int bz = strip / NBY;

    const int t = threadIdx.x;
    const long z = bz;
    const u16* Ab = A + z * batchA + (long)by * 128 * lda;
    const u16* Bb = B + z * batchB + (long)bx * 128 * ldb;

    const int lane = t & 63;
    const int wave = t >> 6;
    const int wm = wave >> 1, wn = wave & 1;      // 2x2 wave grid (64x64 each)
    const int quad = lane >> 4;
    const int frow = lane & 15;
    const int cc0 = quad ^ (frow & 7);            // swizzled chunk col for k-chunk 0

    f32x4 acc[4][4];
#pragma unroll
    for (int i = 0; i < 4; i++)
#pragma unroll
        for (int j = 0; j < 4; j++)
#pragma unroll
            for (int e = 0; e < 4; e++) acc[i][j][e] = 0.f;

    // staging: 1024 chunks of 16B per 16KB tile; thread t does chunks t+j*256.
    // dest chunk d=(r,c8) sources global chunk (r, c8^(r&7)).
    int srow[4], scol[4];
#pragma unroll
    for (int j = 0; j < 4; j++) {
        const int d = t + j * 256;
        srow[j] = d >> 3;
        scol[j] = ((d & 7) ^ (srow[j] & 7)) * 8;
    }

    for (int kt = 0; kt < K; kt += 64) {
#pragma unroll
        for (int j = 0; j < 4; j++)
            gload16(Ab + (long)srow[j] * lda + kt + scol[j], &As[(t + j * 256) * 8]);
#pragma unroll
        for (int j = 0; j < 4; j++)
            gload16(Bb + (long)srow[j] * ldb + kt + scol[j], &Bs[(t + j * 256) * 8]);
        __syncthreads();

#pragma unroll
        for (int kk = 0; kk < 2; kk++) {
            const int cc = (cc0 ^ (kk * 4)) * 8;
            bf16x8 bfr[4];
#pragma unroll
            for (int j = 0; j < 4; j++)
                bfr[j] = *(const bf16x8*)&Bs[(wn * 64 + j * 16 + frow) * 64 + cc];
#pragma unroll
            for (int i = 0; i < 4; i++) {
                bf16x8 af = *(const bf16x8*)&As[(wm * 64 + i * 16 + frow) * 64 + cc];
#pragma unroll
                for (int j = 0; j < 4; j++)
                    acc[i][j] = __builtin_amdgcn_mfma_f32_16x16x32_bf16(af, bfr[j], acc[i][j], 0, 0, 0);
            }
        }
        __syncthreads();
    }

    // epilogue: C/D layout col = lane&15 (n), row = quad*4 + reg (m)  [m89-verified]
    const int m_base = by * 128 + wm * 64;
    const int n_base = bx * 128 + wn * 64;

    if (EPI == 0) {
        const int seg = n_base / 768;             // block-uniform (128 | 768)
        const float* bp = (seg == 0) ? b0 : (seg == 1) ? b1 : b2;
        u16* C = (u16*)Cv + z * batchC;
#pragma unroll
        for (int j = 0; j < 4; j++) {
            const int col = n_base + j * 16 + frow;
            const float bb = bp[col - seg * 768];
#pragma unroll
            for (int i = 0; i < 4; i++) {
                const int row0 = m_base + i * 16 + quad * 4;
#pragma unroll
                for (int r = 0; r < 4; r++)
                    C[(long)(row0 + r) * ldc + col] = f2bf(acc[i][j][r] + bb);
            }
        }
    } else if (EPI == 1) {
        u16* C = (u16*)Cv + z * batchC;
        float rowpart[4][4];
#pragma unroll
        for (int i = 0; i < 4; i++)
#pragma unroll
            for (int r = 0; r < 4; r++) rowpart[i][r] = 0.f;
#pragma unroll
        for (int i = 0; i < 4; i++) {
            const int row0 = m_base + i * 16 + quad * 4;
#pragma unroll
            for (int j = 0; j < 4; j++) {
                const int col = n_base + j * 16 + frow;
#pragma unroll
                for (int r = 0; r < 4; r++) {
                    float e = exp2f(acc[i][j][r] * s2);
                    C[(long)(row0 + r) * ldc + col] = f2bf(e);
                    rowpart[i][r] += e;
                }
            }
        }
        // reduce each row's partial over the 16 frow lanes, then one atomic per row
#pragma unroll
        for (int i = 0; i < 4; i++)
#pragma unroll
            for (int r = 0; r < 4; r++) {
                float v = rowpart[i][r];
                v += __shfl_xor(v, 1); v += __shfl_xor(v, 2);
                v += __shfl_xor(v, 4); v += __shfl_xor(v, 8);
                if (frow == 0)
                    atomicAdd(&rs[z * 4096 + m_base + i * 16 + quad * 4 + r], v);
            }
    } else {
        float* C = (float*)Cv + z * batchC;
#pragma unroll
        for (int i = 0; i < 4; i++) {
            const int row0 = m_base + i * 16 + quad * 4;
            float inv[4];
#pragma unroll
            for (int r = 0; r < 4; r++) inv[r] = 1.0f / rs[z * 4096 + row0 + r];
#pragma unroll
            for (int j = 0; j < 4; j++) {
                const int col = n_base + j * 16 + frow;
#pragma unroll
                for (int r = 0; r < 4; r++)
                    C[(long)(row0 + r) * ldc + col] = acc[i][j][r] * inv[r];
            }
        }
    }
}

extern "C" void kernel_launch(void* const* d_in, const int* in_sizes, int n_in,
                              void* d_out, int out_size, void* d_ws, size_t ws_size,
                              hipStream_t stream) {
    const float* x  = (const float*)d_in[0];
    const float* Wq = (const float*)d_in[1];
    const float* bq = (const float*)d_in[2];
    const float* Wk = (const float*)d_in[3];
    const float* bk = (const float*)d_in[4];
    const float* Wv = (const float*)d_in[5];
    const float* bv = (const float*)d_in[6];
    float* out = (float*)d_out;

    // B=4, S=4096, D=768; 16384 tokens. Workspace layout (total 238,419,968 B):
    //  @0          : xb bf16 [16384][768]      (25,165,824)  -- dead after proj; Vt reuses it
    //  @25,165,824 : QKV bf16 [16384][2304]    (75,497,472)
    //  @100,663,296: E bf16 [4][4096][4096]    (134,217,728)
    //  @234,881,024: Wqkv bf16 [2304][768]     (3,538,944)   -- dead after proj;
    //                 rowsum fp32[16384] (65,536) aliases its head, zeroed in transpose
    uint8_t* ws = (uint8_t*)d_ws;
    u16*   xb   = (u16*)(ws + 0);
    u16*   Vt   = (u16*)(ws + 0);
    u16*   QKV  = (u16*)(ws + 25165824);
    u16*   E    = (u16*)(ws + 100663296);
    u16*   Wqkv = (u16*)(ws + 234881024);
    float* rsum = (float*)(ws + 234881024);

    // 1) casts
    cast_bf16_kernel<<<12288, 256, 0, stream>>>(x, xb, 3145728);
    cast3_bf16_kernel<<<dim3(576, 3), 256, 0, stream>>>(Wq, Wk, Wv, Wqkv);

    // 2) fused QKV projection: [16384,768] x [2304,768]^T + bias -> QKV bf16 (ldc 2304)
    gemm_bt_kernel<0, 18, 2304, 128><<<2304, 256, 0, stream>>>(
        xb, Wqkv, QKV, bq, bk, bv, nullptr, 0.f, 768, 768, 768, 2304, 0, 0, 0);

    // 3) V transpose per batch (V = QKV cols [1536,2304), ld 2304) -> Vt[e][s]; zero rowsum
    transpose_bf16_kernel<<<dim3(24, 128, 4), 256, 0, stream>>>(QKV + 1536, Vt, rsum);

    // 4) E = exp(scale * Q K^T) (per batch, 4096x4096, K=768) + rowsum atomics
    //    s2 = (1/sqrt(768)) * log2(e)
    gemm_bt_kernel<1, 32, 4096, 32><<<4096, 256, 0, stream>>>(
        QKV, QKV + 768, E, nullptr, nullptr, nullptr, rsum, 0.05205954822032348f,
        768, 2304, 2304, 4096, (long)4096 * 2304, (long)4096 * 2304, (long)4096 * 4096);

    // 5) O = (E Vt^T) / rowsum -> fp32 out (per batch, M=4096, N=768, K=4096)
    gemm_bt_kernel<2, 6, 768, 32><<<768, 256, 0, stream>>>(
        E, Vt, out, nullptr, nullptr, nullptr, rsum, 0.f,
        4096, 4096, 4096, 768, (long)4096 * 4096, (long)768 * 4096, (long)4096 * 768);
}

// Round 5
// 412.522 us; speedup vs baseline: 1.4127x; 1.0725x over previous
//
#include <hip/hip_runtime.h>
#include <stdint.h>

typedef unsigned short u16;
typedef __attribute__((ext_vector_type(8))) short    bf16x8;   // 8 bf16 in 4 VGPRs
typedef __attribute__((ext_vector_type(4))) float    f32x4;

// ---------- helpers ----------
__device__ __forceinline__ u16 f2bf(float f) {           // fp32 -> bf16, round-nearest-even
    unsigned u = __float_as_uint(f);
    u = (u + 0x7fffu + ((u >> 16) & 1u)) >> 16;
    return (u16)u;
}

// ---------- fp32 -> bf16 cast (vectorized) ----------
__global__ __launch_bounds__(256) void cast_bf16_kernel(const float* __restrict__ in,
                                                        u16* __restrict__ out, int n4) {
    int i = blockIdx.x * 256 + threadIdx.x;
    if (i < n4) {
        float4 f = ((const float4*)in)[i];
        ushort4 o;
        o.x = f2bf(f.x); o.y = f2bf(f.y); o.z = f2bf(f.z); o.w = f2bf(f.w);
        ((ushort4*)out)[i] = o;
    }
}

// cast the three weight matrices into one concatenated [2304][768] bf16 buffer
__global__ __launch_bounds__(256) void cast3_bf16_kernel(const float* __restrict__ w0,
                                                         const float* __restrict__ w1,
                                                         const float* __restrict__ w2,
                                                         u16* __restrict__ out) {
    const float* src = (blockIdx.y == 0) ? w0 : (blockIdx.y == 1) ? w1 : w2;
    int i = blockIdx.x * 256 + threadIdx.x;          // 576*256 = 147456 = 768*768/4
    float4 f = ((const float4*)src)[i];
    ushort4 o;
    o.x = f2bf(f.x); o.y = f2bf(f.y); o.z = f2bf(f.z); o.w = f2bf(f.w);
    ((ushort4*)out)[(size_t)blockIdx.y * 147456 + i] = o;
}

// ---------- bf16 32x32-tiled transpose: Vt[b][e][s] = V[b][s][e] (ld_in=2304) ----------
// also zeroes the rowsum buffer (it aliases the dead weight buffer; runs after proj GEMM)
__global__ __launch_bounds__(256) void transpose_bf16_kernel(const u16* __restrict__ V,
                                                             u16* __restrict__ Vt,
                                                             float* __restrict__ rsum) {
    __shared__ u16 tile[32][33];
    const int t = threadIdx.x;
    if (blockIdx.x == 0 && blockIdx.z == 0) {
        int idx = blockIdx.y * 256 + t;
        if (idx < 16384) rsum[idx] = 0.f;
    }
    const size_t z = blockIdx.z;
    const u16* Vb  = V  + z * (size_t)4096 * 2304;
    u16*       Vtb = Vt + z * (size_t)768 * 4096;
    const int c0 = blockIdx.x * 32;           // D (col) tile
    const int r0 = blockIdx.y * 32;           // S (row) tile
    const int lr = t >> 3;                    // 0..31
    const int lc = (t & 7) * 4;               // 0..28
    ushort4 in = *(const ushort4*)&Vb[(size_t)(r0 + lr) * 2304 + c0 + lc];
    tile[lr][lc + 0] = in.x; tile[lr][lc + 1] = in.y;
    tile[lr][lc + 2] = in.z; tile[lr][lc + 3] = in.w;
    __syncthreads();
    ushort4 o;
    o.x = tile[lc + 0][lr]; o.y = tile[lc + 1][lr];
    o.z = tile[lc + 2][lr]; o.w = tile[lc + 3][lr];
    *(ushort4*)&Vtb[(size_t)(c0 + lr) * 4096 + r0 + lc] = o;
}

// ---------- GEMM, BK=64, register-staged prefetch: C[m][n] = sum_k A[m][k]*B[n][k] ----------
// 128x128 block tile, BK=64 (32 KB LDS), 4 waves 2x2, each wave 64x64 via 4x4 MFMA 16x16x32.
// Pipeline: tile k+1 is loaded global->VGPR during tile k's MFMA phase (latency hidden),
// then ds_write'd after the compute barrier. LDS single-buffered.
// LDS XOR swizzle: chunk (r,c) holds global chunk (r, c^(r&7)) -- bank-conflict-free
// (verified R4: SQ_LDS_BANK_CONFLICT == 0).
// EPI: 0 = +bias[col] (b0/b1/b2 per 768-col segment), bf16 out            (QKV projection)
//      1 = exp2(acc*s2), bf16 out, atomicAdd row sums into rs             (QK^T -> E)
//      2 = acc * (1/rs[row]), fp32 out                                    (E*Vt -> O)
// Grid 1D = NGRID, two-level XCD swizzle: lin%8 = XCD; within an XCD, bx-group of GRP
// innermost (bxi fastest), strips middle, groups outer -> concurrent working set
// (GRP B-slices + SPX A-strips) sized to fit the 4 MB per-XCD L2.
template <int EPI, int NBX, int GRP, int NGRID, int NBY>
__global__ __launch_bounds__(256, 3) void gemm_bt_kernel(
        const u16* __restrict__ A, const u16* __restrict__ B, void* __restrict__ Cv,
        const float* __restrict__ b0, const float* __restrict__ b1, const float* __restrict__ b2,
        float* __restrict__ rs, float s2, int K,
        int lda, int ldb, int ldc, long batchA, long batchB, long batchC) {
    __shared__ __align__(16) u16 As[128 * 64];
    __shared__ __align__(16) u16 Bs[128 * 64];

    constexpr int SPX = NGRID / (8 * NBX);        // strips per XCD
    const int lin = blockIdx.x;
    const int c = lin & 7, p = lin >> 3;
    const int bxi = p % GRP;
    const int rest = p / GRP;
    const int s = rest % SPX;
    const int g = rest / SPX;
    const int bx = g * GRP + bxi;
    const int strip = c * SPX + s;
    const int by = strip % NBY;
    const int bz = strip / NBY;

    const int t = threadIdx.x;
    const long z = bz;
    const u16* Ab = A + z * batchA + (long)by * 128 * lda;
    const u16* Bb = B + z * batchB + (long)bx * 128 * ldb;

    const int lane = t & 63;
    const int wave = t >> 6;
    const int wm = wave >> 1, wn = wave & 1;      // 2x2 wave grid (64x64 each)
    const int quad = lane >> 4;
    const int frow = lane & 15;
    const int cc0 = quad ^ (frow & 7);            // swizzled chunk col for k-chunk 0

    f32x4 acc[4][4];
#pragma unroll
    for (int i = 0; i < 4; i++)
#pragma unroll
        for (int j = 0; j < 4; j++)
#pragma unroll
            for (int e = 0; e < 4; e++) acc[i][j][e] = 0.f;

    // staging map: 1024 chunks of 16B per 16KB tile; thread t owns dest chunks t+j*256.
    // dest chunk d=(r,c8) sources global chunk (r, c8^(r&7)).
    int srow[4], scol[4];
#pragma unroll
    for (int j = 0; j < 4; j++) {
        const int d = t + j * 256;
        srow[j] = d >> 3;
        scol[j] = ((d & 7) ^ (srow[j] & 7)) * 8;
    }

    // register-staged prefetch buffers (8 x 16B = 32 VGPRs)
    bf16x8 ra[4], rb[4];
#pragma unroll
    for (int j = 0; j < 4; j++) {
        ra[j] = *(const bf16x8*)(Ab + (long)srow[j] * lda + scol[j]);
        rb[j] = *(const bf16x8*)(Bb + (long)srow[j] * ldb + scol[j]);
    }

    for (int kt = 0; kt < K; kt += 64) {
        // commit prefetched tile to LDS (waits on the loads issued one compute-phase ago)
#pragma unroll
        for (int j = 0; j < 4; j++)
            *(bf16x8*)&As[(t + j * 256) * 8] = ra[j];
#pragma unroll
        for (int j = 0; j < 4; j++)
            *(bf16x8*)&Bs[(t + j * 256) * 8] = rb[j];
        __syncthreads();

        // issue next tile's global loads; they fly during the MFMA phase below
        if (kt + 64 < K) {
            const int kn = kt + 64;
#pragma unroll
            for (int j = 0; j < 4; j++) {
                ra[j] = *(const bf16x8*)(Ab + (long)srow[j] * lda + kn + scol[j]);
                rb[j] = *(const bf16x8*)(Bb + (long)srow[j] * ldb + kn + scol[j]);
            }
        }

#pragma unroll
        for (int kk = 0; kk < 2; kk++) {
            const int cc = (cc0 ^ (kk * 4)) * 8;
            bf16x8 bfr[4];
#pragma unroll
            for (int j = 0; j < 4; j++)
                bfr[j] = *(const bf16x8*)&Bs[(wn * 64 + j * 16 + frow) * 64 + cc];
#pragma unroll
            for (int i = 0; i < 4; i++) {
                bf16x8 af = *(const bf16x8*)&As[(wm * 64 + i * 16 + frow) * 64 + cc];
#pragma unroll
                for (int j = 0; j < 4; j++)
                    acc[i][j] = __builtin_amdgcn_mfma_f32_16x16x32_bf16(af, bfr[j], acc[i][j], 0, 0, 0);
            }
        }
        __syncthreads();   // LDS readers done before next iter's ds_write
    }

    // epilogue: C/D layout col = lane&15 (n), row = quad*4 + reg (m)  [m89-verified]
    const int m_base = by * 128 + wm * 64;
    const int n_base = bx * 128 + wn * 64;

    if (EPI == 0) {
        const int seg = n_base / 768;             // block-uniform (128 | 768)
        const float* bp = (seg == 0) ? b0 : (seg == 1) ? b1 : b2;
        u16* C = (u16*)Cv + z * batchC;
#pragma unroll
        for (int j = 0; j < 4; j++) {
            const int col = n_base + j * 16 + frow;
            const float bb = bp[col - seg * 768];
#pragma unroll
            for (int i = 0; i < 4; i++) {
                const int row0 = m_base + i * 16 + quad * 4;
#pragma unroll
                for (int r = 0; r < 4; r++)
                    C[(long)(row0 + r) * ldc + col] = f2bf(acc[i][j][r] + bb);
            }
        }
    } else if (EPI == 1) {
        u16* C = (u16*)Cv + z * batchC;
        float rowpart[4][4];
#pragma unroll
        for (int i = 0; i < 4; i++)
#pragma unroll
            for (int r = 0; r < 4; r++) rowpart[i][r] = 0.f;
#pragma unroll
        for (int i = 0; i < 4; i++) {
            const int row0 = m_base + i * 16 + quad * 4;
#pragma unroll
            for (int j = 0; j < 4; j++) {
                const int col = n_base + j * 16 + frow;
#pragma unroll
                for (int r = 0; r < 4; r++) {
                    float e = exp2f(acc[i][j][r] * s2);
                    C[(long)(row0 + r) * ldc + col] = f2bf(e);
                    rowpart[i][r] += e;
                }
            }
        }
        // reduce each row's partial over the 16 frow lanes, then one atomic per row
#pragma unroll
        for (int i = 0; i < 4; i++)
#pragma unroll
            for (int r = 0; r < 4; r++) {
                float v = rowpart[i][r];
                v += __shfl_xor(v, 1); v += __shfl_xor(v, 2);
                v += __shfl_xor(v, 4); v += __shfl_xor(v, 8);
                if (frow == 0)
                    atomicAdd(&rs[z * 4096 + m_base + i * 16 + quad * 4 + r], v);
            }
    } else {
        float* C = (float*)Cv + z * batchC;
#pragma unroll
        for (int i = 0; i < 4; i++) {
            const int row0 = m_base + i * 16 + quad * 4;
            float inv[4];
#pragma unroll
            for (int r = 0; r < 4; r++) inv[r] = 1.0f / rs[z * 4096 + row0 + r];
#pragma unroll
            for (int j = 0; j < 4; j++) {
                const int col = n_base + j * 16 + frow;
#pragma unroll
                for (int r = 0; r < 4; r++)
                    C[(long)(row0 + r) * ldc + col] = acc[i][j][r] * inv[r];
            }
        }
    }
}

extern "C" void kernel_launch(void* const* d_in, const int* in_sizes, int n_in,
                              void* d_out, int out_size, void* d_ws, size_t ws_size,
                              hipStream_t stream) {
    const float* x  = (const float*)d_in[0];
    const float* Wq = (const float*)d_in[1];
    const float* bq = (const float*)d_in[2];
    const float* Wk = (const float*)d_in[3];
    const float* bk = (const float*)d_in[4];
    const float* Wv = (const float*)d_in[5];
    const float* bv = (const float*)d_in[6];
    float* out = (float*)d_out;

    // B=4, S=4096, D=768; 16384 tokens. Workspace layout (total 238,419,968 B):
    //  @0          : xb bf16 [16384][768]      (25,165,824)  -- dead after proj; Vt reuses it
    //  @25,165,824 : QKV bf16 [16384][2304]    (75,497,472)
    //  @100,663,296: E bf16 [4][4096][4096]    (134,217,728)
    //  @234,881,024: Wqkv bf16 [2304][768]     (3,538,944)   -- dead after proj;
    //                 rowsum fp32[16384] (65,536) aliases its head, zeroed in transpose
    uint8_t* ws = (uint8_t*)d_ws;
    u16*   xb   = (u16*)(ws + 0);
    u16*   Vt   = (u16*)(ws + 0);
    u16*   QKV  = (u16*)(ws + 25165824);
    u16*   E    = (u16*)(ws + 100663296);
    u16*   Wqkv = (u16*)(ws + 234881024);
    float* rsum = (float*)(ws + 234881024);

    // 1) casts
    cast_bf16_kernel<<<12288, 256, 0, stream>>>(x, xb, 3145728);
    cast3_bf16_kernel<<<dim3(576, 3), 256, 0, stream>>>(Wq, Wk, Wv, Wqkv);

    // 2) fused QKV projection: [16384,768] x [2304,768]^T + bias -> QKV bf16 (ldc 2304)
    //    GRP=6: concurrent set = 6 W-slices (1.2 MB) + 16 x-strips (3.1 MB) ~ L2
    gemm_bt_kernel<0, 18, 6, 2304, 128><<<2304, 256, 0, stream>>>(
        xb, Wqkv, QKV, bq, bk, bv, nullptr, 0.f, 768, 768, 768, 2304, 0, 0, 0);

    // 3) V transpose per batch (V = QKV cols [1536,2304), ld 2304) -> Vt[e][s]; zero rowsum
    transpose_bf16_kernel<<<dim3(24, 128, 4), 256, 0, stream>>>(QKV + 1536, Vt, rsum);

    // 4) E = exp(scale * Q K^T) (per batch, 4096x4096, K=768) + rowsum atomics
    //    s2 = (1/sqrt(768)) * log2(e); GRP=8: 8 K-slices (1.5 MB) + 16 Q-strips (3.1 MB) ~ L2
    gemm_bt_kernel<1, 32, 8, 4096, 32><<<4096, 256, 0, stream>>>(
        QKV, QKV + 768, E, nullptr, nullptr, nullptr, rsum, 0.05205954822032348f,
        768, 2304, 2304, 4096, (long)4096 * 2304, (long)4096 * 2304, (long)4096 * 4096);

    // 5) O = (E Vt^T) / rowsum -> fp32 out (per batch, M=4096, N=768, K=4096)
    gemm_bt_kernel<2, 6, 6, 768, 32><<<768, 256, 0, stream>>>(
        E, Vt, out, nullptr, nullptr, nullptr, rsum, 0.f,
        4096, 4096, 4096, 768, (long)4096 * 4096, (long)768 * 4096, (long)4096 * 768);
}